// Round 1
// baseline (616.446 us; speedup 1.0000x reference)
//
#include <hip/hip_runtime.h>
#include <hip/hip_bf16.h>

#define L_SZ 200
#define RB 8

__device__ __forceinline__ unsigned short f2bf(float f) {
    unsigned int u = __float_as_uint(f);
    unsigned int r = (u + 0x7fffu + ((u >> 16) & 1u)) >> 16;
    return (unsigned short)r;
}
__device__ __forceinline__ float bf2f(unsigned short h) {
    return __uint_as_float(((unsigned int)h) << 16);
}
__device__ __forceinline__ float wave_sum64(float v) {
    #pragma unroll
    for (int m = 1; m <= 32; m <<= 1) v += __shfl_xor(v, m, 64);
    return v;
}
__device__ __forceinline__ float wave_max64(float v) {
    #pragma unroll
    for (int m = 1; m <= 32; m <<= 1) v = fmaxf(v, __shfl_xor(v, m, 64));
    return v;
}

// One block per batch element b. 256 threads = 4 waves; wave w handles rows
// l = w, w+4, ... Layer-0 folded to per-batch 64x64 W_eff (see launch comment).
__global__ __launch_bounds__(256) void attn_kernel(
    const int* __restrict__ item_id, const int* __restrict__ hist_seq,
    const float* __restrict__ item_W, const float* __restrict__ hist_W,
    const float* __restrict__ aW0, const float* __restrict__ ab0,
    const float* __restrict__ aW1, const float* __restrict__ ab1,
    const float* __restrict__ aW2, const float* __restrict__ ab2,
    float* __restrict__ pooled_ws)
{
    __shared__ __align__(16) float weff[64][64];    // 16 KB, build scratch
    __shared__ __align__(16) float stag[4][64];     // per-wave fp32 hist staging
    __shared__ __align__(16) float hsh[4][64];      // per-wave layer-0 output
    __shared__ __align__(16) float iemb[64];
    __shared__ __align__(16) float scores[L_SZ];
    __shared__ __align__(16) float pools[4][64];    // c_b partials, then pooled partials
    __shared__ __align__(16) float red[8];
    __shared__ __align__(16) int   seq_sh[L_SZ];
    __shared__ __align__(16) unsigned short arch[L_SZ * 64];  // bf16 hist archive

    const int tid  = threadIdx.x;
    const int w    = tid >> 6;
    const int lane = tid & 63;
    const int b    = blockIdx.x;
    const int* hseq = hist_seq + b * L_SZ;

    if (tid < 64)   iemb[tid]   = item_W[(size_t)item_id[b] * 64 + tid];
    if (tid < L_SZ) seq_sh[tid] = hseq[tid];
    __syncthreads();

    // W_eff[k][j] = aW0[k][j] + aW0[192+k][j] + iemb[k]*aW0[128+k][j]  (cooperative)
    #pragma unroll 4
    for (int it = 0; it < 16; ++it) {
        int idx = it * 256 + tid;
        int k = idx >> 6, j = idx & 63;
        weff[k][j] = aW0[k * 64 + j] + aW0[(192 + k) * 64 + j]
                   + iemb[k] * aW0[(128 + k) * 64 + j];
    }
    // c_b partials: wave w covers k in [16w, 16w+16)
    {
        float c = 0.f;
        #pragma unroll 4
        for (int t = 0; t < 16; ++t) {
            int k = w * 16 + t;
            c = fmaf(iemb[k], aW0[(64 + k) * 64 + lane] - aW0[(192 + k) * 64 + lane], c);
        }
        pools[w][lane] = c;
    }
    __syncthreads();

    const float cbr = ab0[lane]
        + ((pools[0][lane] + pools[1][lane]) + (pools[2][lane] + pools[3][lane]));

    // kick off first gather before the register-load bursts
    int seq_c = seq_sh[w];
    float hv_c = hist_W[(size_t)seq_c * 64 + lane];

    // lane j holds W_eff column j; half-wave split of aW1 columns
    float wcol[64];
    #pragma unroll
    for (int k = 0; k < 64; ++k) wcol[k] = weff[k][lane];

    const int jj = lane & 31;
    const int half = lane >> 5;
    float a1r[32];
    #pragma unroll
    for (int t = 0; t < 32; ++t) a1r[t] = aW1[(half * 32 + t) * 32 + jj];
    const float aw2r = aW2[jj];
    const float ab1r = ab1[jj];
    const float ab2s = ab2[0];

    // main loop: 50 iters/wave, no barriers (all LDS traffic is wave-private)
    for (int base = 0; base < L_SZ; base += 4) {
        const int lc  = base + w;
        const int lnx = lc + 4;
        int seq_n = 0; float hv_n = 0.f;
        if (lnx < L_SZ) {                      // software prefetch next row
            seq_n = seq_sh[lnx];
            hv_n  = hist_W[(size_t)seq_n * 64 + lane];
        }
        stag[w][lane] = hv_c;
        arch[lc * 64 + lane] = f2bf(hv_c);

        // layer 0: 64x64 matvec, weights in registers, hist via b128 broadcast
        const float4* st4 = (const float4*)stag[w];
        float p0 = cbr, p1 = 0.f, p2 = 0.f, p3 = 0.f;
        #pragma unroll
        for (int k4 = 0; k4 < 16; ++k4) {
            float4 h4 = st4[k4];
            p0 = fmaf(h4.x, wcol[4 * k4 + 0], p0);
            p1 = fmaf(h4.y, wcol[4 * k4 + 1], p1);
            p2 = fmaf(h4.z, wcol[4 * k4 + 2], p2);
            p3 = fmaf(h4.w, wcol[4 * k4 + 3], p3);
        }
        hsh[w][lane] = fmaxf((p0 + p1) + (p2 + p3), 0.f);

        // layer 1: 64->32, each output split across lane pairs (j, j+32)
        const float4* hh4 = (const float4*)(&hsh[w][half * 32]);
        float q0 = 0.f, q1 = 0.f, q2 = 0.f, q3 = 0.f;
        #pragma unroll
        for (int t4 = 0; t4 < 8; ++t4) {
            float4 h4 = hh4[t4];
            q0 = fmaf(h4.x, a1r[4 * t4 + 0], q0);
            q1 = fmaf(h4.y, a1r[4 * t4 + 1], q1);
            q2 = fmaf(h4.z, a1r[4 * t4 + 2], q2);
            q3 = fmaf(h4.w, a1r[4 * t4 + 3], q3);
        }
        float accq = (q0 + q1) + (q2 + q3);
        float full = accq + __shfl_xor(accq, 32, 64);
        float h1v  = fmaxf(full + ab1r, 0.f);

        // layer 2: 32->1 via wave reduction
        float val = (half == 0) ? h1v * aw2r : 0.f;
        val = wave_sum64(val);
        if (lane == 0)
            scores[lc] = (seq_c == 0) ? -1.0e9f : (val + ab2s);

        seq_c = seq_n;
        hv_c  = hv_n;
    }
    __syncthreads();

    // masked softmax over 200 scores
    float s0 = (tid < L_SZ) ? scores[tid] : -3.0e38f;
    float mx = wave_max64(s0);
    if (lane == 0) red[w] = mx;
    __syncthreads();
    mx = fmaxf(fmaxf(red[0], red[1]), fmaxf(red[2], red[3]));
    float e = (tid < L_SZ) ? __expf(s0 - mx) : 0.f;
    float sm = wave_sum64(e);
    if (lane == 0) red[4 + w] = sm;
    __syncthreads();
    const float winv = 1.f / ((red[4] + red[5]) + (red[6] + red[7]));
    if (tid < L_SZ) scores[tid] = e * winv;
    __syncthreads();

    // pooled[j] = sum_l w_l * hist[l][j]  (wave w reads the rows it archived)
    float pa = 0.f;
    for (int l = w; l < L_SZ; l += 4)
        pa = fmaf(scores[l], bf2f(arch[l * 64 + lane]), pa);
    pools[w][lane] = pa;
    __syncthreads();
    if (w == 0) {
        pooled_ws[(size_t)b * 64 + lane] =
            (pools[0][lane] + pools[1][lane]) + (pools[2][lane] + pools[3][lane]);
    }
}

// Main MLP: 244 -> 256 -> 128 -> 1 -> sigmoid. One block per RB=8 rows
// (register blocking amortizes mW0/mW1 reads 8x).
__global__ __launch_bounds__(256) void mlp_kernel(
    const int* __restrict__ user_id, const int* __restrict__ item_id,
    const int* __restrict__ item_cat, const int* __restrict__ item_dur,
    const float* __restrict__ user_dense, const float* __restrict__ item_dense,
    const float* __restrict__ user_W, const float* __restrict__ item_W,
    const float* __restrict__ cat_W, const float* __restrict__ dur_W,
    const float* __restrict__ mW0, const float* __restrict__ mb0,
    const float* __restrict__ mW1, const float* __restrict__ mb1,
    const float* __restrict__ mW2, const float* __restrict__ mb2,
    const float* __restrict__ pooled_ws, float* __restrict__ out)
{
    __shared__ __align__(16) float xT[244][RB];   // x transposed: [feature][row]
    __shared__ __align__(16) float h0T[256][RB];
    __shared__ __align__(16) float h1T[128][RB];
    __shared__ __align__(16) float part[128][RB];

    const int tid = threadIdx.x;
    const int b0 = blockIdx.x * RB;

    // assemble x = [u_emb|i_emb|c_emb|d_emb|user_dense|item_dense|pooled]
    for (int idx = tid; idx < 244 * RB; idx += 256) {
        int r = idx / 244;
        int c = idx - r * 244;
        int b = b0 + r;
        float v;
        if (c < 64)       v = user_W[(size_t)user_id[b] * 64 + c];
        else if (c < 128) v = item_W[(size_t)item_id[b] * 64 + (c - 64)];
        else if (c < 144) v = cat_W[item_cat[b] * 16 + (c - 128)];
        else if (c < 152) v = dur_W[item_dur[b] * 8 + (c - 144)];
        else if (c < 177) v = user_dense[b * 25 + (c - 152)];
        else if (c < 180) v = item_dense[b * 3 + (c - 177)];
        else              v = pooled_ws[(size_t)b * 64 + (c - 180)];
        xT[c][r] = v;
    }
    __syncthreads();

    // layer 1: thread j computes out0[j] for all 8 rows
    {
        float acc[RB];
        const float bias = mb0[tid];
        #pragma unroll
        for (int r = 0; r < RB; ++r) acc[r] = bias;
        #pragma unroll 4
        for (int k = 0; k < 244; ++k) {
            float wk = mW0[k * 256 + tid];
            float4 xa = *(const float4*)&xT[k][0];
            float4 xb = *(const float4*)&xT[k][4];
            acc[0] = fmaf(wk, xa.x, acc[0]);
            acc[1] = fmaf(wk, xa.y, acc[1]);
            acc[2] = fmaf(wk, xa.z, acc[2]);
            acc[3] = fmaf(wk, xa.w, acc[3]);
            acc[4] = fmaf(wk, xb.x, acc[4]);
            acc[5] = fmaf(wk, xb.y, acc[5]);
            acc[6] = fmaf(wk, xb.z, acc[6]);
            acc[7] = fmaf(wk, xb.w, acc[7]);
        }
        #pragma unroll
        for (int r = 0; r < RB; ++r) h0T[tid][r] = fmaxf(acc[r], 0.f);
    }
    __syncthreads();

    // layer 2: output jj (<128) split across two k-halves
    const int jj = tid & 127;
    const int half = tid >> 7;
    {
        float acc[RB];
        #pragma unroll
        for (int r = 0; r < RB; ++r) acc[r] = 0.f;
        #pragma unroll 4
        for (int t = 0; t < 128; ++t) {
            int k = half * 128 + t;
            float wk = mW1[k * 128 + jj];
            float4 ha = *(const float4*)&h0T[k][0];
            float4 hb = *(const float4*)&h0T[k][4];
            acc[0] = fmaf(wk, ha.x, acc[0]);
            acc[1] = fmaf(wk, ha.y, acc[1]);
            acc[2] = fmaf(wk, ha.z, acc[2]);
            acc[3] = fmaf(wk, ha.w, acc[3]);
            acc[4] = fmaf(wk, hb.x, acc[4]);
            acc[5] = fmaf(wk, hb.y, acc[5]);
            acc[6] = fmaf(wk, hb.z, acc[6]);
            acc[7] = fmaf(wk, hb.w, acc[7]);
        }
        if (half == 1) {
            #pragma unroll
            for (int r = 0; r < RB; ++r) part[jj][r] = acc[r];
        }
        __syncthreads();
        if (half == 0) {
            const float bias = mb1[jj];
            #pragma unroll
            for (int r = 0; r < RB; ++r)
                h1T[jj][r] = fmaxf(acc[r] + part[jj][r] + bias, 0.f);
        }
    }
    __syncthreads();

    // layer 3 + sigmoid
    if (tid < RB) {
        const int r = tid;
        float a0 = mb2[0], a1 = 0.f;
        #pragma unroll 8
        for (int k = 0; k < 128; k += 2) {
            a0 = fmaf(h1T[k][r],     mW2[k],     a0);
            a1 = fmaf(h1T[k + 1][r], mW2[k + 1], a1);
        }
        float a = a0 + a1;
        out[b0 + r] = 1.f / (1.f + __expf(-a));
    }
}

extern "C" void kernel_launch(void* const* d_in, const int* in_sizes, int n_in,
                              void* d_out, int out_size, void* d_ws, size_t ws_size,
                              hipStream_t stream) {
    (void)in_sizes; (void)n_in; (void)out_size; (void)ws_size;
    const int*   user_id    = (const int*)d_in[0];
    const int*   item_id    = (const int*)d_in[1];
    const int*   item_cat   = (const int*)d_in[2];
    const int*   item_dur   = (const int*)d_in[3];
    const float* user_dense = (const float*)d_in[4];
    const float* item_dense = (const float*)d_in[5];
    const int*   hist_seq   = (const int*)d_in[6];
    const float* user_W     = (const float*)d_in[7];
    const float* item_W     = (const float*)d_in[8];
    const float* cat_W      = (const float*)d_in[9];
    const float* dur_W      = (const float*)d_in[10];
    const float* hist_W     = (const float*)d_in[11];
    const float* aW0 = (const float*)d_in[12];
    const float* ab0 = (const float*)d_in[13];
    const float* aW1 = (const float*)d_in[14];
    const float* ab1 = (const float*)d_in[15];
    const float* aW2 = (const float*)d_in[16];
    const float* ab2 = (const float*)d_in[17];
    const float* mW0 = (const float*)d_in[18];
    const float* mb0 = (const float*)d_in[19];
    const float* mW1 = (const float*)d_in[20];
    const float* mb1 = (const float*)d_in[21];
    const float* mW2 = (const float*)d_in[22];
    const float* mb2 = (const float*)d_in[23];
    float* out = (float*)d_out;
    float* pooled_ws = (float*)d_ws;   // 4096*64 floats = 1 MB

    attn_kernel<<<4096, 256, 0, stream>>>(item_id, hist_seq, item_W, hist_W,
                                          aW0, ab0, aW1, ab1, aW2, ab2, pooled_ws);
    mlp_kernel<<<4096 / RB, 256, 0, stream>>>(user_id, item_id, item_cat, item_dur,
                                              user_dense, item_dense,
                                              user_W, item_W, cat_W, dur_W,
                                              mW0, mb0, mW1, mb1, mW2, mb2,
                                              pooled_ws, out);
}

// Round 2
// 451.431 us; speedup vs baseline: 1.3655x; 1.3655x over previous
//
#include <hip/hip_runtime.h>
#include <hip/hip_bf16.h>

#define L_SZ 200
#define RB 8
#define HS_STRIDE 72   // bf16 elems per H row: 64 + 8 pad (144 B, 16B-aligned, 2-way banks)

typedef __attribute__((ext_vector_type(8))) short short8;   // 8 bf16 = 4 VGPRs (MFMA A/B frag)
typedef __attribute__((ext_vector_type(4))) float floatx4;  // MFMA C/D frag

__device__ __forceinline__ unsigned short f2bf(float f) {
    unsigned int u = __float_as_uint(f);
    unsigned int r = (u + 0x7fffu + ((u >> 16) & 1u)) >> 16;
    return (unsigned short)r;
}
__device__ __forceinline__ float bf2f(unsigned short h) {
    return __uint_as_float(((unsigned int)h) << 16);
}
__device__ __forceinline__ float wave_sum64(float v) {
    #pragma unroll
    for (int m = 1; m <= 32; m <<= 1) v += __shfl_xor(v, m, 64);
    return v;
}
__device__ __forceinline__ float wave_max64(float v) {
    #pragma unroll
    for (int m = 1; m <= 32; m <<= 1) v = fmaxf(v, __shfl_xor(v, m, 64));
    return v;
}
__device__ __forceinline__ unsigned int pk2(float a, float b) {
    return ((unsigned int)f2bf(b) << 16) | (unsigned int)f2bf(a);
}

// One block per batch element. 256 thr = 4 waves. Layer0 folded to 64x64 W_eff:
//   feat@aW0 = H@(aW0[0:64]+aW0[192:256]+iemb*aW0[128:192]) + const(iemb) + ab0
// Layer0/1 via mfma_f32_16x16x32_bf16, 13 M-tiles of 16 rows (200 padded to 208).
__global__ __launch_bounds__(256) void attn_kernel(
    const int* __restrict__ item_id, const int* __restrict__ hist_seq,
    const float* __restrict__ item_W, const float* __restrict__ hist_W,
    const float* __restrict__ aW0, const float* __restrict__ ab0,
    const float* __restrict__ aW1, const float* __restrict__ ab1,
    const float* __restrict__ aW2, const float* __restrict__ ab2,
    float* __restrict__ pooled_ws)
{
    // manual LDS carve (53664 B total -> 3 blocks/CU)
    __shared__ __align__(16) unsigned char smem[53664];
    unsigned short* Hs  = (unsigned short*)(smem);           // 208 x 72 bf16 (29952 B)
    unsigned short* WeT = (unsigned short*)(smem + 29952);   // 64 x 64 bf16 WeffT (8192 B)
    unsigned short* W1T = (unsigned short*)(smem + 38144);   // 32 x 64 bf16 aW1T (4096 B)
    unsigned short* scr = (unsigned short*)(smem + 42240);   // 4 x (16 x 72) bf16 (9216 B)
    float* pools        = (float*)(smem + 42240);            // 8 x 64 f32 OVERLAYS scr
    float* scores       = (float*)(smem + 51456);            // 208 f32
    float* iemb         = (float*)(smem + 52288);            // 64 f32
    float* cb           = (float*)(smem + 52544);            // 64 f32
    int*   seq_sh       = (int*)(smem + 52800);              // 208 i32
    float* red          = (float*)(smem + 53632);            // 8 f32

    const int tid  = threadIdx.x;
    const int w    = tid >> 6;
    const int lane = tid & 63;
    const int b    = blockIdx.x;
    const int* hseq = hist_seq + b * L_SZ;

    if (tid < 64)  iemb[tid]   = item_W[(size_t)item_id[b] * 64 + tid];
    if (tid < 208) seq_sh[tid] = (tid < L_SZ) ? hseq[tid] : 0;
    __syncthreads();

    // ---- stage H (gather hist rows, fp32 -> bf16), rows 200..207 zeroed ----
    for (int u = tid; u < 208 * 8; u += 256) {
        int row = u >> 3, c8 = u & 7;
        float4 f0 = {0.f,0.f,0.f,0.f}, f1 = {0.f,0.f,0.f,0.f};
        if (row < L_SZ) {
            const float* src = hist_W + (size_t)seq_sh[row] * 64 + c8 * 8;
            f0 = *(const float4*)src;
            f1 = *(const float4*)(src + 4);
        }
        uint4 pk;
        pk.x = pk2(f0.x, f0.y); pk.y = pk2(f0.z, f0.w);
        pk.z = pk2(f1.x, f1.y); pk.w = pk2(f1.z, f1.w);
        *(uint4*)(Hs + row * HS_STRIDE + c8 * 8) = pk;
    }

    // ---- build WeffT[j][k] = aW0[k][j] + aW0[192+k][j] + iemb[k]*aW0[128+k][j] ----
    for (int u = tid; u < 512; u += 256) {
        int j = u >> 3, k8 = u & 7;
        float4 ie0 = *(const float4*)&iemb[k8 * 8];
        float4 ie1 = *(const float4*)&iemb[k8 * 8 + 4];
        float ie[8] = {ie0.x, ie0.y, ie0.z, ie0.w, ie1.x, ie1.y, ie1.z, ie1.w};
        float v[8];
        #pragma unroll
        for (int i = 0; i < 8; ++i) {
            int k = k8 * 8 + i;
            v[i] = aW0[k * 64 + j] + aW0[(192 + k) * 64 + j]
                 + ie[i] * aW0[(128 + k) * 64 + j];
        }
        uint4 pk;
        pk.x = pk2(v[0], v[1]); pk.y = pk2(v[2], v[3]);
        pk.z = pk2(v[4], v[5]); pk.w = pk2(v[6], v[7]);
        *(uint4*)(WeT + j * 64 + k8 * 8) = pk;
    }

    // ---- build aW1T[n][k] (32 x 64) ----
    {
        int n = tid >> 3, k8 = tid & 7;
        float v[8];
        #pragma unroll
        for (int i = 0; i < 8; ++i) v[i] = aW1[(k8 * 8 + i) * 32 + n];
        uint4 pk;
        pk.x = pk2(v[0], v[1]); pk.y = pk2(v[2], v[3]);
        pk.z = pk2(v[4], v[5]); pk.w = pk2(v[6], v[7]);
        *(uint4*)(W1T + n * 64 + k8 * 8) = pk;
    }

    // ---- cb[j] = ab0[j] + sum_k iemb[k]*(aW0[64+k][j] - aW0[192+k][j]) ----
    {
        float cpart = 0.f;
        #pragma unroll 4
        for (int t = 0; t < 16; ++t) {
            int k = w * 16 + t;
            cpart = fmaf(iemb[k], aW0[(64 + k) * 64 + lane] - aW0[(192 + k) * 64 + lane], cpart);
        }
        pools[w * 64 + lane] = cpart;   // pools overlays scr: scr not yet in use
    }
    __syncthreads();
    if (tid < 64)
        cb[tid] = ab0[tid] + ((pools[tid] + pools[64 + tid]) + (pools[128 + tid] + pools[192 + tid]));
    __syncthreads();

    // ---- hoist B fragments into registers ----
    const int c = lane & 15, q = lane >> 4;
    short8 bW[4][2], bW1[2][2];
    #pragma unroll
    for (int nt = 0; nt < 4; ++nt)
        #pragma unroll
        for (int ks = 0; ks < 2; ++ks)
            bW[nt][ks] = *(const short8*)(WeT + (nt * 16 + c) * 64 + ks * 32 + q * 8);
    #pragma unroll
    for (int nt = 0; nt < 2; ++nt)
        #pragma unroll
        for (int ks = 0; ks < 2; ++ks)
            bW1[nt][ks] = *(const short8*)(W1T + (nt * 16 + c) * 64 + ks * 32 + q * 8);
    float cbr[4];
    #pragma unroll
    for (int nt = 0; nt < 4; ++nt) cbr[nt] = cb[nt * 16 + c];
    float ab1r[2], aw2r[2];
    #pragma unroll
    for (int nt = 0; nt < 2; ++nt) {
        ab1r[nt] = ab1[nt * 16 + c];
        aw2r[nt] = aW2[nt * 16 + c];
    }
    const float ab2s = ab2[0];
    unsigned short* scrw = scr + w * (16 * HS_STRIDE);
    const floatx4 zf = {0.f, 0.f, 0.f, 0.f};

    // ---- main: per M-tile  layer0 MFMA -> relu -> scr -> layer1 MFMA -> score ----
    for (int mt = w; mt < 13; mt += 4) {
        const int rowbase = mt * 16;
        floatx4 acc0[4] = {zf, zf, zf, zf};
        #pragma unroll
        for (int ks = 0; ks < 2; ++ks) {
            short8 a = *(const short8*)(Hs + (rowbase + c) * HS_STRIDE + ks * 32 + q * 8);
            acc0[0] = __builtin_amdgcn_mfma_f32_16x16x32_bf16(a, bW[0][ks], acc0[0], 0, 0, 0);
            acc0[1] = __builtin_amdgcn_mfma_f32_16x16x32_bf16(a, bW[1][ks], acc0[1], 0, 0, 0);
            acc0[2] = __builtin_amdgcn_mfma_f32_16x16x32_bf16(a, bW[2][ks], acc0[2], 0, 0, 0);
            acc0[3] = __builtin_amdgcn_mfma_f32_16x16x32_bf16(a, bW[3][ks], acc0[3], 0, 0, 0);
        }
        // epilogue: +cb, relu, bf16, C-layout (col=lane&15,row=q*4+r) -> row-major scr
        #pragma unroll
        for (int nt = 0; nt < 4; ++nt)
            #pragma unroll
            for (int r = 0; r < 4; ++r) {
                float h = fmaxf(acc0[nt][r] + cbr[nt], 0.f);
                scrw[(q * 4 + r) * HS_STRIDE + nt * 16 + c] = f2bf(h);
            }
        floatx4 acc1[2] = {zf, zf};
        #pragma unroll
        for (int ks = 0; ks < 2; ++ks) {
            short8 a1 = *(const short8*)(scrw + c * HS_STRIDE + ks * 32 + q * 8);
            acc1[0] = __builtin_amdgcn_mfma_f32_16x16x32_bf16(a1, bW1[0][ks], acc1[0], 0, 0, 0);
            acc1[1] = __builtin_amdgcn_mfma_f32_16x16x32_bf16(a1, bW1[1][ks], acc1[1], 0, 0, 0);
        }
        // layer2: relu -> *aW2 -> reduce over the 16 col-lanes
        float s[4];
        #pragma unroll
        for (int r = 0; r < 4; ++r)
            s[r] = fmaxf(acc1[0][r] + ab1r[0], 0.f) * aw2r[0]
                 + fmaxf(acc1[1][r] + ab1r[1], 0.f) * aw2r[1];
        #pragma unroll
        for (int m = 1; m <= 8; m <<= 1)
            #pragma unroll
            for (int r = 0; r < 4; ++r) s[r] += __shfl_xor(s[r], m, 64);
        if (c == 0) {
            #pragma unroll
            for (int r = 0; r < 4; ++r) {
                int l = rowbase + q * 4 + r;
                if (l < L_SZ)
                    scores[l] = (seq_sh[l] == 0) ? -1.0e9f : (s[r] + ab2s);
            }
        }
    }
    __syncthreads();

    // ---- masked softmax over 200 scores ----
    float s0 = (tid < L_SZ) ? scores[tid] : -3.0e38f;
    float mx = wave_max64(s0);
    if (lane == 0) red[w] = mx;
    __syncthreads();
    mx = fmaxf(fmaxf(red[0], red[1]), fmaxf(red[2], red[3]));
    float e = (tid < L_SZ) ? __expf(s0 - mx) : 0.f;
    float sm = wave_sum64(e);
    if (lane == 0) red[4 + w] = sm;
    __syncthreads();
    const float winv = 1.f / ((red[4] + red[5]) + (red[6] + red[7]));
    if (tid < L_SZ) scores[tid] = e * winv;
    __syncthreads();

    // ---- pooled[j] = sum_l w_l * H[l][j]; 8 row-groups x (2 cols / lane) ----
    {
        int g  = (w << 1) | (lane >> 5);
        int jj = lane & 31;
        int l0 = g * 26, l1 = (l0 + 26 < L_SZ) ? l0 + 26 : L_SZ;
        float p0 = 0.f, p1 = 0.f;
        for (int l = l0; l < l1; ++l) {
            float wt = scores[l];
            unsigned int pv = *(const unsigned int*)(Hs + l * HS_STRIDE + jj * 2);
            p0 = fmaf(wt, bf2f((unsigned short)(pv & 0xffffu)), p0);
            p1 = fmaf(wt, bf2f((unsigned short)(pv >> 16)), p1);
        }
        float2 pp = {p0, p1};
        *(float2*)&pools[g * 64 + jj * 2] = pp;   // scr is dead by now
    }
    __syncthreads();
    if (tid < 64) {
        float sum = 0.f;
        #pragma unroll
        for (int g = 0; g < 8; ++g) sum += pools[g * 64 + tid];
        pooled_ws[(size_t)b * 64 + tid] = sum;
    }
}

// Main MLP: 244 -> 256 -> 128 -> 1 -> sigmoid. One block per RB=8 rows.
__global__ __launch_bounds__(256) void mlp_kernel(
    const int* __restrict__ user_id, const int* __restrict__ item_id,
    const int* __restrict__ item_cat, const int* __restrict__ item_dur,
    const float* __restrict__ user_dense, const float* __restrict__ item_dense,
    const float* __restrict__ user_W, const float* __restrict__ item_W,
    const float* __restrict__ cat_W, const float* __restrict__ dur_W,
    const float* __restrict__ mW0, const float* __restrict__ mb0,
    const float* __restrict__ mW1, const float* __restrict__ mb1,
    const float* __restrict__ mW2, const float* __restrict__ mb2,
    const float* __restrict__ pooled_ws, float* __restrict__ out)
{
    __shared__ __align__(16) float xT[244][RB];
    __shared__ __align__(16) float h0T[256][RB];
    __shared__ __align__(16) float h1T[128][RB];
    __shared__ __align__(16) float part[128][RB];

    const int tid = threadIdx.x;
    const int b0 = blockIdx.x * RB;

    for (int idx = tid; idx < 244 * RB; idx += 256) {
        int r = idx / 244;
        int c = idx - r * 244;
        int b = b0 + r;
        float v;
        if (c < 64)       v = user_W[(size_t)user_id[b] * 64 + c];
        else if (c < 128) v = item_W[(size_t)item_id[b] * 64 + (c - 64)];
        else if (c < 144) v = cat_W[item_cat[b] * 16 + (c - 128)];
        else if (c < 152) v = dur_W[item_dur[b] * 8 + (c - 144)];
        else if (c < 177) v = user_dense[b * 25 + (c - 152)];
        else if (c < 180) v = item_dense[b * 3 + (c - 177)];
        else              v = pooled_ws[(size_t)b * 64 + (c - 180)];
        xT[c][r] = v;
    }
    __syncthreads();

    {
        float acc[RB];
        const float bias = mb0[tid];
        #pragma unroll
        for (int r = 0; r < RB; ++r) acc[r] = bias;
        #pragma unroll 4
        for (int k = 0; k < 244; ++k) {
            float wk = mW0[k * 256 + tid];
            float4 xa = *(const float4*)&xT[k][0];
            float4 xb = *(const float4*)&xT[k][4];
            acc[0] = fmaf(wk, xa.x, acc[0]);
            acc[1] = fmaf(wk, xa.y, acc[1]);
            acc[2] = fmaf(wk, xa.z, acc[2]);
            acc[3] = fmaf(wk, xa.w, acc[3]);
            acc[4] = fmaf(wk, xb.x, acc[4]);
            acc[5] = fmaf(wk, xb.y, acc[5]);
            acc[6] = fmaf(wk, xb.z, acc[6]);
            acc[7] = fmaf(wk, xb.w, acc[7]);
        }
        #pragma unroll
        for (int r = 0; r < RB; ++r) h0T[tid][r] = fmaxf(acc[r], 0.f);
    }
    __syncthreads();

    const int jj = tid & 127;
    const int half = tid >> 7;
    {
        float acc[RB];
        #pragma unroll
        for (int r = 0; r < RB; ++r) acc[r] = 0.f;
        #pragma unroll 4
        for (int t = 0; t < 128; ++t) {
            int k = half * 128 + t;
            float wk = mW1[k * 128 + jj];
            float4 ha = *(const float4*)&h0T[k][0];
            float4 hb = *(const float4*)&h0T[k][4];
            acc[0] = fmaf(wk, ha.x, acc[0]);
            acc[1] = fmaf(wk, ha.y, acc[1]);
            acc[2] = fmaf(wk, ha.z, acc[2]);
            acc[3] = fmaf(wk, ha.w, acc[3]);
            acc[4] = fmaf(wk, hb.x, acc[4]);
            acc[5] = fmaf(wk, hb.y, acc[5]);
            acc[6] = fmaf(wk, hb.z, acc[6]);
            acc[7] = fmaf(wk, hb.w, acc[7]);
        }
        if (half == 1) {
            #pragma unroll
            for (int r = 0; r < RB; ++r) part[jj][r] = acc[r];
        }
        __syncthreads();
        if (half == 0) {
            const float bias = mb1[jj];
            #pragma unroll
            for (int r = 0; r < RB; ++r)
                h1T[jj][r] = fmaxf(acc[r] + part[jj][r] + bias, 0.f);
        }
    }
    __syncthreads();

    if (tid < RB) {
        const int r = tid;
        float a0 = mb2[0], a1 = 0.f;
        #pragma unroll 8
        for (int k = 0; k < 128; k += 2) {
            a0 = fmaf(h1T[k][r],     mW2[k],     a0);
            a1 = fmaf(h1T[k + 1][r], mW2[k + 1], a1);
        }
        float a = a0 + a1;
        out[b0 + r] = 1.f / (1.f + __expf(-a));
    }
}

extern "C" void kernel_launch(void* const* d_in, const int* in_sizes, int n_in,
                              void* d_out, int out_size, void* d_ws, size_t ws_size,
                              hipStream_t stream) {
    (void)in_sizes; (void)n_in; (void)out_size; (void)ws_size;
    const int*   user_id    = (const int*)d_in[0];
    const int*   item_id    = (const int*)d_in[1];
    const int*   item_cat   = (const int*)d_in[2];
    const int*   item_dur   = (const int*)d_in[3];
    const float* user_dense = (const float*)d_in[4];
    const float* item_dense = (const float*)d_in[5];
    const int*   hist_seq   = (const int*)d_in[6];
    const float* user_W     = (const float*)d_in[7];
    const float* item_W     = (const float*)d_in[8];
    const float* cat_W      = (const float*)d_in[9];
    const float* dur_W      = (const float*)d_in[10];
    const float* hist_W     = (const float*)d_in[11];
    const float* aW0 = (const float*)d_in[12];
    const float* ab0 = (const float*)d_in[13];
    const float* aW1 = (const float*)d_in[14];
    const float* ab1 = (const float*)d_in[15];
    const float* aW2 = (const float*)d_in[16];
    const float* ab2 = (const float*)d_in[17];
    const float* mW0 = (const float*)d_in[18];
    const float* mb0 = (const float*)d_in[19];
    const float* mW1 = (const float*)d_in[20];
    const float* mb1 = (const float*)d_in[21];
    const float* mW2 = (const float*)d_in[22];
    const float* mb2 = (const float*)d_in[23];
    float* out = (float*)d_out;
    float* pooled_ws = (float*)d_ws;   // 4096*64 floats = 1 MB

    attn_kernel<<<4096, 256, 0, stream>>>(item_id, hist_seq, item_W, hist_W,
                                          aW0, ab0, aW1, ab1, aW2, ab2, pooled_ws);
    mlp_kernel<<<4096 / RB, 256, 0, stream>>>(user_id, item_id, item_cat, item_dur,
                                              user_dense, item_dense,
                                              user_W, item_W, cat_W, dur_W,
                                              mW0, mb0, mW1, mb1, mW2, mb2,
                                              pooled_ws, out);
}

// Round 3
// 431.153 us; speedup vs baseline: 1.4298x; 1.0470x over previous
//
#include <hip/hip_runtime.h>
#include <hip/hip_bf16.h>

#define L_SZ 200
#define RB 8
#define HS_STRIDE 72   // bf16 elems per H row: 64 + 8 pad (144 B, 16B-aligned)

typedef __attribute__((ext_vector_type(8))) short short8;   // 8 bf16 = 4 VGPRs (MFMA A/B frag)
typedef __attribute__((ext_vector_type(4))) float floatx4;  // MFMA C/D frag

__device__ __forceinline__ unsigned short f2bf(float f) {
    unsigned int u = __float_as_uint(f);
    unsigned int r = (u + 0x7fffu + ((u >> 16) & 1u)) >> 16;
    return (unsigned short)r;
}
__device__ __forceinline__ float bf2f(unsigned short h) {
    return __uint_as_float(((unsigned int)h) << 16);
}
__device__ __forceinline__ float wave_sum64(float v) {
    #pragma unroll
    for (int m = 1; m <= 32; m <<= 1) v += __shfl_xor(v, m, 64);
    return v;
}
__device__ __forceinline__ float wave_max64(float v) {
    #pragma unroll
    for (int m = 1; m <= 32; m <<= 1) v = fmaxf(v, __shfl_xor(v, m, 64));
    return v;
}
__device__ __forceinline__ unsigned int pk2(float a, float b) {
    return ((unsigned int)f2bf(b) << 16) | (unsigned int)f2bf(a);
}

// One block per batch element. 256 thr = 4 waves. Layer0 folded to 64x64 W_eff.
// LDS diet: 39136 B -> 4 blocks/CU (was 53664 -> 3). Region B (8 KB) is
// time-multiplexed: WeT (build+hoist) -> scr (main loop) -> pools (pooling).
// WeT/scr use XOR-8-group swizzle: elem = row*64 + ((col>>3 ^ (row&7))*8) + (col&7)
// -> all b128 reads/writes <=2-way bank aliasing (free).
__global__ __launch_bounds__(256, 4) void attn_kernel(
    const int* __restrict__ item_id, const int* __restrict__ hist_seq,
    const float* __restrict__ item_W, const float* __restrict__ hist_W,
    const float* __restrict__ aW0, const float* __restrict__ ab0,
    const float* __restrict__ aW1, const float* __restrict__ ab1,
    const float* __restrict__ aW2, const float* __restrict__ ab2,
    float* __restrict__ pooled_ws)
{
    __shared__ __align__(16) unsigned char smem[39136];
    unsigned short* Hs  = (unsigned short*)(smem);           // 200 x 72 bf16 = 28800 B
    unsigned short* BB  = (unsigned short*)(smem + 28800);   // 8192 B multiplexed
    int*   seq_sh = (int*)(smem + 36992);                    // 200 i32 = 800 B
    float* scores = (float*)(smem + 37792);                  // 200 f32 (cb scratch early)
    float* iemb   = (float*)(smem + 38592);                  // 64 f32
    float* cb     = (float*)(smem + 38848);                  // 64 f32
    float* red    = (float*)(smem + 39104);                  // 8 f32

    const int tid  = threadIdx.x;
    const int w    = tid >> 6;
    const int lane = tid & 63;
    const int b    = blockIdx.x;
    const int* hseq = hist_seq + b * L_SZ;

    if (tid < 64)   iemb[tid]   = item_W[(size_t)item_id[b] * 64 + tid];
    if (tid < L_SZ) seq_sh[tid] = hseq[tid];
    __syncthreads();

    // ---- P2: stage Hs (gathers issue earliest) + WeT build + cb partials ----
    for (int u = tid; u < L_SZ * 8; u += 256) {
        int row = u >> 3, c8 = u & 7;
        const float* src = hist_W + (size_t)seq_sh[row] * 64 + c8 * 8;
        float4 f0 = *(const float4*)src;
        float4 f1 = *(const float4*)(src + 4);
        uint4 pk;
        pk.x = pk2(f0.x, f0.y); pk.y = pk2(f0.z, f0.w);
        pk.z = pk2(f1.x, f1.y); pk.w = pk2(f1.z, f1.w);
        *(uint4*)(Hs + row * HS_STRIDE + c8 * 8) = pk;
    }
    // WeT[j][k] = aW0[k][j] + aW0[192+k][j] + iemb[k]*aW0[128+k][j], swizzled
    for (int u = tid; u < 512; u += 256) {
        int j = u >> 3, k8 = u & 7;
        float v[8];
        #pragma unroll
        for (int i = 0; i < 8; ++i) {
            int k = k8 * 8 + i;
            v[i] = aW0[k * 64 + j] + aW0[(192 + k) * 64 + j]
                 + iemb[k] * aW0[(128 + k) * 64 + j];
        }
        uint4 pk;
        pk.x = pk2(v[0], v[1]); pk.y = pk2(v[2], v[3]);
        pk.z = pk2(v[4], v[5]); pk.w = pk2(v[6], v[7]);
        *(uint4*)(BB + j * 64 + (k8 ^ (j & 7)) * 8) = pk;
    }
    // cb partials (waves 0,1; 32 k each) -> scores region as scratch
    if (w < 2) {
        float cpart = 0.f;
        #pragma unroll 4
        for (int t = 0; t < 32; ++t) {
            int k = w * 32 + t;
            cpart = fmaf(iemb[k], aW0[(64 + k) * 64 + lane] - aW0[(192 + k) * 64 + lane], cpart);
        }
        scores[w * 64 + lane] = cpart;
    }
    // bW1 direct register build: frag elem i -> k = ks*32+q*8+i, n = nt*16+c
    const int c = lane & 15, q = lane >> 4;
    short8 bW1[2][2];
    #pragma unroll
    for (int nt = 0; nt < 2; ++nt)
        #pragma unroll
        for (int ks = 0; ks < 2; ++ks) {
            unsigned short tmp[8];
            #pragma unroll
            for (int i = 0; i < 8; ++i)
                tmp[i] = f2bf(aW1[(ks * 32 + q * 8 + i) * 32 + nt * 16 + c]);
            bW1[nt][ks] = *(short8*)tmp;
        }
    float ab1r[2], aw2r[2];
    #pragma unroll
    for (int nt = 0; nt < 2; ++nt) {
        ab1r[nt] = ab1[nt * 16 + c];
        aw2r[nt] = aW2[nt * 16 + c];
    }
    const float ab2s = ab2[0];
    __syncthreads();

    // ---- P4: hoist bW frags from swizzled WeT; finalize cb ----
    short8 bW[4][2];
    #pragma unroll
    for (int nt = 0; nt < 4; ++nt)
        #pragma unroll
        for (int ks = 0; ks < 2; ++ks)
            bW[nt][ks] = *(const short8*)(BB + (nt * 16 + c) * 64
                                             + ((4 * ks + q) ^ (c & 7)) * 8);
    if (tid < 64)
        cb[tid] = ab0[tid] + scores[tid] + scores[64 + tid];
    __syncthreads();

    float cbr[4];
    #pragma unroll
    for (int nt = 0; nt < 4; ++nt) cbr[nt] = cb[nt * 16 + c];
    unsigned short* scrw = BB + w * (16 * 64);
    const floatx4 zf = {0.f, 0.f, 0.f, 0.f};

    // ---- main: per M-tile  layer0 MFMA -> relu -> scr -> layer1 MFMA -> score ----
    // (tile 12 rows 200..207 read garbage beyond Hs -> rows are independent, masked)
    for (int mt = w; mt < 13; mt += 4) {
        const int rowbase = mt * 16;
        floatx4 acc0[4] = {zf, zf, zf, zf};
        #pragma unroll
        for (int ks = 0; ks < 2; ++ks) {
            short8 a = *(const short8*)(Hs + (rowbase + c) * HS_STRIDE + ks * 32 + q * 8);
            acc0[0] = __builtin_amdgcn_mfma_f32_16x16x32_bf16(a, bW[0][ks], acc0[0], 0, 0, 0);
            acc0[1] = __builtin_amdgcn_mfma_f32_16x16x32_bf16(a, bW[1][ks], acc0[1], 0, 0, 0);
            acc0[2] = __builtin_amdgcn_mfma_f32_16x16x32_bf16(a, bW[2][ks], acc0[2], 0, 0, 0);
            acc0[3] = __builtin_amdgcn_mfma_f32_16x16x32_bf16(a, bW[3][ks], acc0[3], 0, 0, 0);
        }
        // epilogue: +cb, relu, bf16; C-layout (col=c,row=q*4+r) -> swizzled scr
        #pragma unroll
        for (int nt = 0; nt < 4; ++nt)
            #pragma unroll
            for (int r = 0; r < 4; ++r) {
                float h = fmaxf(acc0[nt][r] + cbr[nt], 0.f);
                int row = q * 4 + r;
                int gp = (2 * nt + (c >> 3)) ^ (row & 7);
                scrw[row * 64 + gp * 8 + (c & 7)] = f2bf(h);
            }
        floatx4 acc1[2] = {zf, zf};
        #pragma unroll
        for (int ks = 0; ks < 2; ++ks) {
            short8 a1 = *(const short8*)(scrw + c * 64 + ((4 * ks + q) ^ (c & 7)) * 8);
            acc1[0] = __builtin_amdgcn_mfma_f32_16x16x32_bf16(a1, bW1[0][ks], acc1[0], 0, 0, 0);
            acc1[1] = __builtin_amdgcn_mfma_f32_16x16x32_bf16(a1, bW1[1][ks], acc1[1], 0, 0, 0);
        }
        // layer2: relu -> *aW2 -> reduce over the 16 col-lanes
        float s[4];
        #pragma unroll
        for (int r = 0; r < 4; ++r)
            s[r] = fmaxf(acc1[0][r] + ab1r[0], 0.f) * aw2r[0]
                 + fmaxf(acc1[1][r] + ab1r[1], 0.f) * aw2r[1];
        #pragma unroll
        for (int m = 1; m <= 8; m <<= 1)
            #pragma unroll
            for (int r = 0; r < 4; ++r) s[r] += __shfl_xor(s[r], m, 64);
        if (c == 0) {
            #pragma unroll
            for (int r = 0; r < 4; ++r) {
                int l = rowbase + q * 4 + r;
                if (l < L_SZ)
                    scores[l] = (seq_sh[l] == 0) ? -1.0e9f : (s[r] + ab2s);
            }
        }
    }
    __syncthreads();

    // ---- masked softmax over 200 scores ----
    float s0 = (tid < L_SZ) ? scores[tid] : -3.0e38f;
    float mx = wave_max64(s0);
    if (lane == 0) red[w] = mx;
    __syncthreads();
    mx = fmaxf(fmaxf(red[0], red[1]), fmaxf(red[2], red[3]));
    float e = (tid < L_SZ) ? __expf(s0 - mx) : 0.f;
    float sm = wave_sum64(e);
    if (lane == 0) red[4 + w] = sm;
    __syncthreads();
    const float winv = 1.f / ((red[4] + red[5]) + (red[6] + red[7]));
    if (tid < L_SZ) scores[tid] = e * winv;
    __syncthreads();

    // ---- pooled[j] = sum_l w_l * H[l][j]; 8 row-groups x (2 cols / lane) ----
    float* pools = (float*)BB;   // scr dead now
    {
        int g  = (w << 1) | (lane >> 5);
        int jj = lane & 31;
        int l0 = g * 26, l1 = (l0 + 26 < L_SZ) ? l0 + 26 : L_SZ;
        float p0 = 0.f, p1 = 0.f;
        for (int l = l0; l < l1; ++l) {
            float wt = scores[l];
            unsigned int pv = *(const unsigned int*)(Hs + l * HS_STRIDE + jj * 2);
            p0 = fmaf(wt, bf2f((unsigned short)(pv & 0xffffu)), p0);
            p1 = fmaf(wt, bf2f((unsigned short)(pv >> 16)), p1);
        }
        float2 pp = {p0, p1};
        *(float2*)&pools[g * 64 + jj * 2] = pp;
    }
    __syncthreads();
    if (tid < 64) {
        float sum = 0.f;
        #pragma unroll
        for (int g = 0; g < 8; ++g) sum += pools[g * 64 + tid];
        pooled_ws[(size_t)b * 64 + tid] = sum;
    }
}

// Main MLP: 244 -> 256 -> 128 -> 1 -> sigmoid. One block per RB=8 rows.
__global__ __launch_bounds__(256) void mlp_kernel(
    const int* __restrict__ user_id, const int* __restrict__ item_id,
    const int* __restrict__ item_cat, const int* __restrict__ item_dur,
    const float* __restrict__ user_dense, const float* __restrict__ item_dense,
    const float* __restrict__ user_W, const float* __restrict__ item_W,
    const float* __restrict__ cat_W, const float* __restrict__ dur_W,
    const float* __restrict__ mW0, const float* __restrict__ mb0,
    const float* __restrict__ mW1, const float* __restrict__ mb1,
    const float* __restrict__ mW2, const float* __restrict__ mb2,
    const float* __restrict__ pooled_ws, float* __restrict__ out)
{
    __shared__ __align__(16) float xT[244][RB];
    __shared__ __align__(16) float h0T[256][RB];
    __shared__ __align__(16) float h1T[128][RB];
    __shared__ __align__(16) float part[128][RB];

    const int tid = threadIdx.x;
    const int b0 = blockIdx.x * RB;

    for (int idx = tid; idx < 244 * RB; idx += 256) {
        int r = idx / 244;
        int c = idx - r * 244;
        int b = b0 + r;
        float v;
        if (c < 64)       v = user_W[(size_t)user_id[b] * 64 + c];
        else if (c < 128) v = item_W[(size_t)item_id[b] * 64 + (c - 64)];
        else if (c < 144) v = cat_W[item_cat[b] * 16 + (c - 128)];
        else if (c < 152) v = dur_W[item_dur[b] * 8 + (c - 144)];
        else if (c < 177) v = user_dense[b * 25 + (c - 152)];
        else if (c < 180) v = item_dense[b * 3 + (c - 177)];
        else              v = pooled_ws[(size_t)b * 64 + (c - 180)];
        xT[c][r] = v;
    }
    __syncthreads();

    {
        float acc[RB];
        const float bias = mb0[tid];
        #pragma unroll
        for (int r = 0; r < RB; ++r) acc[r] = bias;
        #pragma unroll 4
        for (int k = 0; k < 244; ++k) {
            float wk = mW0[k * 256 + tid];
            float4 xa = *(const float4*)&xT[k][0];
            float4 xb = *(const float4*)&xT[k][4];
            acc[0] = fmaf(wk, xa.x, acc[0]);
            acc[1] = fmaf(wk, xa.y, acc[1]);
            acc[2] = fmaf(wk, xa.z, acc[2]);
            acc[3] = fmaf(wk, xa.w, acc[3]);
            acc[4] = fmaf(wk, xb.x, acc[4]);
            acc[5] = fmaf(wk, xb.y, acc[5]);
            acc[6] = fmaf(wk, xb.z, acc[6]);
            acc[7] = fmaf(wk, xb.w, acc[7]);
        }
        #pragma unroll
        for (int r = 0; r < RB; ++r) h0T[tid][r] = fmaxf(acc[r], 0.f);
    }
    __syncthreads();

    const int jj = tid & 127;
    const int half = tid >> 7;
    {
        float acc[RB];
        #pragma unroll
        for (int r = 0; r < RB; ++r) acc[r] = 0.f;
        #pragma unroll 4
        for (int t = 0; t < 128; ++t) {
            int k = half * 128 + t;
            float wk = mW1[k * 128 + jj];
            float4 ha = *(const float4*)&h0T[k][0];
            float4 hb = *(const float4*)&h0T[k][4];
            acc[0] = fmaf(wk, ha.x, acc[0]);
            acc[1] = fmaf(wk, ha.y, acc[1]);
            acc[2] = fmaf(wk, ha.z, acc[2]);
            acc[3] = fmaf(wk, ha.w, acc[3]);
            acc[4] = fmaf(wk, hb.x, acc[4]);
            acc[5] = fmaf(wk, hb.y, acc[5]);
            acc[6] = fmaf(wk, hb.z, acc[6]);
            acc[7] = fmaf(wk, hb.w, acc[7]);
        }
        if (half == 1) {
            #pragma unroll
            for (int r = 0; r < RB; ++r) part[jj][r] = acc[r];
        }
        __syncthreads();
        if (half == 0) {
            const float bias = mb1[jj];
            #pragma unroll
            for (int r = 0; r < RB; ++r)
                h1T[jj][r] = fmaxf(acc[r] + part[jj][r] + bias, 0.f);
        }
    }
    __syncthreads();

    if (tid < RB) {
        const int r = tid;
        float a0 = mb2[0], a1 = 0.f;
        #pragma unroll 8
        for (int k = 0; k < 128; k += 2) {
            a0 = fmaf(h1T[k][r],     mW2[k],     a0);
            a1 = fmaf(h1T[k + 1][r], mW2[k + 1], a1);
        }
        float a = a0 + a1;
        out[b0 + r] = 1.f / (1.f + __expf(-a));
    }
}

extern "C" void kernel_launch(void* const* d_in, const int* in_sizes, int n_in,
                              void* d_out, int out_size, void* d_ws, size_t ws_size,
                              hipStream_t stream) {
    (void)in_sizes; (void)n_in; (void)out_size; (void)ws_size;
    const int*   user_id    = (const int*)d_in[0];
    const int*   item_id    = (const int*)d_in[1];
    const int*   item_cat   = (const int*)d_in[2];
    const int*   item_dur   = (const int*)d_in[3];
    const float* user_dense = (const float*)d_in[4];
    const float* item_dense = (const float*)d_in[5];
    const int*   hist_seq   = (const int*)d_in[6];
    const float* user_W     = (const float*)d_in[7];
    const float* item_W     = (const float*)d_in[8];
    const float* cat_W      = (const float*)d_in[9];
    const float* dur_W      = (const float*)d_in[10];
    const float* hist_W     = (const float*)d_in[11];
    const float* aW0 = (const float*)d_in[12];
    const float* ab0 = (const float*)d_in[13];
    const float* aW1 = (const float*)d_in[14];
    const float* ab1 = (const float*)d_in[15];
    const float* aW2 = (const float*)d_in[16];
    const float* ab2 = (const float*)d_in[17];
    const float* mW0 = (const float*)d_in[18];
    const float* mb0 = (const float*)d_in[19];
    const float* mW1 = (const float*)d_in[20];
    const float* mb1 = (const float*)d_in[21];
    const float* mW2 = (const float*)d_in[22];
    const float* mb2 = (const float*)d_in[23];
    float* out = (float*)d_out;
    float* pooled_ws = (float*)d_ws;   // 4096*64 floats = 1 MB

    attn_kernel<<<4096, 256, 0, stream>>>(item_id, hist_seq, item_W, hist_W,
                                          aW0, ab0, aW1, ab1, aW2, ab2, pooled_ws);
    mlp_kernel<<<4096 / RB, 256, 0, stream>>>(user_id, item_id, item_cat, item_dur,
                                              user_dense, item_dense,
                                              user_W, item_W, cat_W, dur_W,
                                              mW0, mb0, mW1, mb1, mW2, mb2,
                                              pooled_ws, out);
}